// Round 6
// baseline (579.378 us; speedup 1.0000x reference)
//
#include <hip/hip_runtime.h>
#include <hip/hip_bf16.h>

// GGNN fused scan v5. B=128, N=128, E=64, T=32, R=32.
// ggnn_pre: 257 blocks. Blocks 0..255: 4 waves x 16 rows, barrier-free
//   readlane matvecs (wr/wz/wt 96 + win 64 per-lane cols), 1-row prefetch.
//   Writes NTbf (bf16) + Hbf (bf16). Block 256: relWbG = b_in + rel@W_in_bot.
// ggnn_main: 1 block/batch, 256 thr, TWO barriers/step:
//   max phase: H2/relWb bf16 [row][128B]; lane handles j-group (e>>3),
//     e-slice (e&7)*8 via b128 reads; shfl_xor 3-round max; quarter-max
//     to pmaxQ (w0..w3).
//   gate phase: ALL waves redundantly compute r,z,t,upd via readlane
//     (wr,wz,wt,win = 256 VGPR/thread); w3 additionally writes H2 row i.
//   NT prefetched 1 step ahead (crosses 2 barriers before use).
//   user/item/sub tracked in regs. Steps i>=len are exact no-ops.

#define B_ 128
#define N_ 128

typedef unsigned short u16;
typedef unsigned int u32;

__device__ __forceinline__ float b2f(u16 u) {
    union { u32 i; float f; } c; c.i = ((u32)u) << 16; return c.f;
}
__device__ __forceinline__ u16 f2b(float f) {
    union { float f; u32 i; } c; c.f = f;
    u32 u = c.i;
    return (u16)((u + 0x7fffu + ((u >> 16) & 1u)) >> 16);
}
__device__ __forceinline__ float lo16(u32 d) { return __int_as_float(d << 16); }
__device__ __forceinline__ float hi16(u32 d) { return __int_as_float(d & 0xffff0000u); }
__device__ __forceinline__ float sigmoidf_(float x) { return 1.0f / (1.0f + __expf(-x)); }
__device__ __forceinline__ float tanhf_(float x) { return 1.0f - 2.0f / (__expf(2.0f * x) + 1.0f); }
__device__ __forceinline__ float rlane(float v, int k) {
    return __int_as_float(__builtin_amdgcn_readlane(__float_as_int(v), k));
}

// ---------------- precompute kernel ----------------
__global__ __launch_bounds__(256, 1) void ggnn_pre(
    const int* __restrict__ node_slice, const int* __restrict__ type_slice,
    const float* __restrict__ emb_table, const float* __restrict__ type_table,
    const float* __restrict__ W_in, const float* __restrict__ b_in,
    const float* __restrict__ rel_table,
    const float* __restrict__ Wr, const float* __restrict__ br,
    const float* __restrict__ Wz, const float* __restrict__ bz,
    const float* __restrict__ Wt, const float* __restrict__ bt,
    u16* __restrict__ NTbf, u16* __restrict__ Hbf, u16* __restrict__ relWbG)
{
    const int t = threadIdx.x;
    if (blockIdx.x == 256) {                      // relWb table (shared by all b)
        for (int idx = t; idx < 51 * 64; idx += 256) {
            int r = idx >> 6, ee = idx & 63;
            float acc = b_in[ee];
            #pragma unroll
            for (int k = 0; k < 32; ++k)
                acc += rel_table[r * 32 + k] * W_in[(64 + k) * 64 + ee];
            relWbG[idx] = f2b(acc);
        }
        return;
    }
    const int w = t >> 6;
    const int e = t & 63;
    const int wv = blockIdx.x * 4 + w;            // 1024 waves x 16 rows = 16384

    float wr[96], wz[96], wt[96], win[64];
    #pragma unroll
    for (int k = 0; k < 96; ++k) {
        wr[k] = Wr[k * 64 + e];
        wz[k] = Wz[k * 64 + e];
        wt[k] = Wt[k * 64 + e];
    }
    #pragma unroll
    for (int k = 0; k < 64; ++k) win[k] = W_in[k * 64 + e];
    const float brv = br[e], bzv = bz[e], btv = bt[e];

    // prefetch row 0
    int node = node_slice[wv * 16];
    int typ  = type_slice[wv * 16];
    float xe = emb_table[node * 64 + e];
    float xt = type_table[typ * 32 + (e & 31)];

    for (int rr = 0; rr < 16; ++rr) {
        const int row = wv * 16 + rr;
        const float cxe = xe, cxt = xt;
        if (rr < 15) {                            // prefetch next row (no barriers ->
            node = node_slice[row + 1];           //  loads stay in flight over matvec)
            typ  = type_slice[row + 1];
            xe = emb_table[node * 64 + e];
            xt = type_table[typ * 32 + (e & 31)];
        }
        float ar = brv, az = bzv, at_ = btv, ah = 0.f;
        #pragma unroll
        for (int k = 0; k < 32; ++k) {
            float xk = rlane(cxt, k);
            ar = fmaf(xk, wr[k], ar);
            az = fmaf(xk, wz[k], az);
            at_ = fmaf(xk, wt[k], at_);
        }
        #pragma unroll
        for (int k = 0; k < 64; ++k) {
            float xk = rlane(cxe, k);
            ar = fmaf(xk, wr[32 + k], ar);
            az = fmaf(xk, wz[32 + k], az);
            at_ = fmaf(xk, wt[32 + k], at_);
            ah = fmaf(xk, win[k], ah);
        }
        NTbf[row * 192 + e]       = f2b(ar);
        NTbf[row * 192 + 64 + e]  = f2b(az);
        NTbf[row * 192 + 128 + e] = f2b(at_);
        Hbf[row * 64 + e]         = f2b(ah);
    }
}

// ---------------- main scan kernel ----------------
__global__ __launch_bounds__(256, 1) void ggnn_main(
    const int* __restrict__ rel_matrix,
    const int* __restrict__ input_length, const float* __restrict__ distance,
    const float* __restrict__ Wr, const float* __restrict__ Wz,
    const float* __restrict__ Wt, const float* __restrict__ W_in,
    const float* __restrict__ W_co, const float* __restrict__ b_co,
    const float* __restrict__ W1, const float* __restrict__ b1,
    const float* __restrict__ W2, const float* __restrict__ b2,
    const float* __restrict__ W3, const float* __restrict__ b3,
    const float* __restrict__ W4, const float* __restrict__ b4,
    const u16* __restrict__ NTbf, const u16* __restrict__ Hbf,
    const u16* __restrict__ relWbG,
    float* __restrict__ out)
{
    __shared__ __align__(16) u16 H2[N_ * 64];              // 16 KB bf16 [j][e]
    __shared__ __align__(16) u16 relWb16[51 * 64];         // 6.4 KB bf16 [r][e]
    __shared__ __align__(16) unsigned char relL[N_ * N_];  // 16 KB len-masked
    __shared__ __align__(16) float pmaxQ[4 * 64];
    __shared__ __align__(16) float disc[N_];
    __shared__ __align__(16) float userrow[64], itemrow[64], submrow[64];
    __shared__ __align__(16) float temp[192];
    __shared__ float h1[128];
    __shared__ float h2v[64];
    __shared__ float h3v[32];

    const int b = blockIdx.x;
    const int t = threadIdx.x;
    const int w = t >> 6;
    const int e = t & 63;       // lane id == e
    const int jg = e >> 3;      // j-group within wave (max phase)
    const int es = e & 7;       // e-slice within row (max phase)
    const int len = input_length[b];
    const float NEGINF = -__builtin_inff();

    // ---- staging ----
    if (t < N_) disc[t] = -0.1f * distance[b * N_ + t];
    {   // rel_matrix -> u8, len-masked
        const int4* src = (const int4*)(rel_matrix + b * N_ * N_);
        u32* dst = (u32*)relL;
        for (int c = t; c < 4096; c += 256) {
            int4 v = src[c];
            int j = (c * 4) & 127;
            u32 p = (u32)((j + 0 < len && v.x) ? v.x : 0)
                  | ((u32)((j + 1 < len && v.y) ? v.y : 0) << 8)
                  | ((u32)((j + 2 < len && v.z) ? v.z : 0) << 16)
                  | ((u32)((j + 3 < len && v.w) ? v.w : 0) << 24);
            dst[c] = p;
        }
    }
    {   // H2 <- Hbf (bf16 direct copy)
        const u32* src = (const u32*)(Hbf + b * N_ * 64);
        u32* dst = (u32*)H2;
        for (int c = t; c < 2048; c += 256) dst[c] = src[c];
    }
    {   // relWb16 <- relWbG
        const u32* src = (const u32*)relWbG;
        u32* dst = (u32*)relWb16;
        for (int c = t; c < 1632; c += 256) dst[c] = src[c];
    }

    // gate weight columns: ALL waves hold all four (redundant gate compute)
    float wr[64], wz[64], wt[64], win[64];
    #pragma unroll
    for (int k = 0; k < 64; ++k) {
        wr[k]  = Wr[(96 + k) * 64 + e];
        wz[k]  = Wz[(96 + k) * 64 + e];
        wt[k]  = Wt[(96 + k) * 64 + e];
        win[k] = W_in[k * 64 + e];
    }

    // NT for step 0
    const u16* NTb = NTbf + b * N_ * 192;
    u16 ntr = NTb[e], ntz = NTb[64 + e], ntt = NTb[128 + e];
    float user_r = 0.f, item_r = 0.f, subm_r = NEGINF;
    __syncthreads();                                       // staging done

    float dj[4];
    #pragma unroll
    for (int g = 0; g < 4; ++g) dj[g] = disc[w * 32 + g * 8 + jg];
    const int hofs = es * 8;    // u16 offset within a 64-elem row

    // ---- scan: 2 barriers per step ----
    for (int i = 0; i < len; ++i) {
        // max phase: lane covers j = w*32+g*8+jg, e-slice es*8..es*8+7
        int rj[4];
        #pragma unroll
        for (int g = 0; g < 4; ++g) rj[g] = relL[i * 128 + w * 32 + g * 8 + jg];

        float mq[8];
        #pragma unroll
        for (int q = 0; q < 8; ++q) mq[q] = NEGINF;

        #pragma unroll
        for (int g = 0; g < 4; ++g) {
            const int j = w * 32 + g * 8 + jg;
            uint4 hv = *(const uint4*)(H2 + j * 64 + hofs);
            uint4 qv = *(const uint4*)(relWb16 + rj[g] * 64 + hofs);
            const float d = dj[g];
            const float bias = rj[g] ? 0.f : NEGINF;
            mq[0] = fmaxf(mq[0], fmaxf(lo16(hv.x) + lo16(qv.x), 0.f) * d + bias);
            mq[1] = fmaxf(mq[1], fmaxf(hi16(hv.x) + hi16(qv.x), 0.f) * d + bias);
            mq[2] = fmaxf(mq[2], fmaxf(lo16(hv.y) + lo16(qv.y), 0.f) * d + bias);
            mq[3] = fmaxf(mq[3], fmaxf(hi16(hv.y) + hi16(qv.y), 0.f) * d + bias);
            mq[4] = fmaxf(mq[4], fmaxf(lo16(hv.z) + lo16(qv.z), 0.f) * d + bias);
            mq[5] = fmaxf(mq[5], fmaxf(hi16(hv.z) + hi16(qv.z), 0.f) * d + bias);
            mq[6] = fmaxf(mq[6], fmaxf(lo16(hv.w) + lo16(qv.w), 0.f) * d + bias);
            mq[7] = fmaxf(mq[7], fmaxf(hi16(hv.w) + hi16(qv.w), 0.f) * d + bias);
        }
        // reduce across the 8 j-groups of this wave
        #pragma unroll
        for (int dlt = 8; dlt < 64; dlt <<= 1) {
            #pragma unroll
            for (int q = 0; q < 8; ++q)
                mq[q] = fmaxf(mq[q], __shfl_xor(mq[q], dlt, 64));
        }
        if (jg == 0) {          // lanes 0..7 publish quarter-max (es = e)
            *(float4*)(pmaxQ + w * 64 + es * 8)     = make_float4(mq[0], mq[1], mq[2], mq[3]);
            *(float4*)(pmaxQ + w * 64 + es * 8 + 4) = make_float4(mq[4], mq[5], mq[6], mq[7]);
        }
        __syncthreads();                                   // B

        float dis0 = fmaxf(fmaxf(pmaxQ[e], pmaxQ[64 + e]),
                           fmaxf(pmaxQ[128 + e], pmaxQ[192 + e]));
        dis0 = (dis0 == NEGINF) ? 0.f : dis0;

        // NT prefetch for step i+1 (crosses barrier A; ~700 cyc to land)
        const int ip = (i + 1) & 127;
        u16 ntrp = NTb[ip * 192 + e];
        u16 ntzp = NTb[ip * 192 + 64 + e];
        u16 nttp = NTb[ip * 192 + 128 + e];

        // gates: redundant in every wave (readlane matvecs, zero LDS)
        float ar = b2f(ntr), az = b2f(ntz);
        #pragma unroll
        for (int k = 0; k < 64; ++k) {
            float xk = rlane(dis0, k);
            ar = fmaf(xk, wr[k], ar);
            az = fmaf(xk, wz[k], az);
        }
        float r = sigmoidf_(ar);
        float z = sigmoidf_(az);
        float rdp = r * dis0;
        float at_ = b2f(ntt);
        #pragma unroll
        for (int k = 0; k < 64; ++k) {
            float xk = rlane(rdp, k);
            at_ = fmaf(xk, wt[k], at_);
        }
        float hh = tanhf_(at_);
        float upd = (1.f - z) * dis0 + z * hh;
        if (i == 0) user_r = upd;
        item_r = upd;
        subm_r = fmaxf(subm_r, upd);

        if (w == 3) {                                      // H-row update
            float ah = 0.f;
            #pragma unroll
            for (int k = 0; k < 64; ++k)
                ah = fmaf(rlane(upd, k), win[k], ah);
            H2[i * 64 + e] = f2b(ah);
        }
        ntr = ntrp; ntz = ntzp; ntt = nttp;
        __syncthreads();                                   // A (H2 row i ready)
    }

    if (w == 0) { userrow[e] = user_r; itemrow[e] = item_r; submrow[e] = subm_r; }
    __syncthreads();

    // ---- epilogue ----
    if (t < 128) {
        const int half = t >> 6;                // 0: ua*user, 1: ia*item
        const float* row = (half == 0) ? userrow : itemrow;
        float acc = b_co[e];
        #pragma unroll
        for (int k = 0; k < 64; ++k) acc += row[k] * W_co[k * 64 + e];
        #pragma unroll
        for (int k = 0; k < 64; ++k) acc += submrow[k] * W_co[(64 + k) * 64 + e];
        float act = fmaxf(acc, 0.f);
        temp[half * 128 + e] = act * row[e];
    } else if (t < 192) {
        temp[64 + (t - 128)] = submrow[t - 128];
    }
    __syncthreads();

    if (t < 128) {
        float acc = b1[t];
        for (int k = 0; k < 192; ++k) acc += temp[k] * W1[k * 128 + t];
        h1[t] = fmaxf(acc, 0.f);
    }
    __syncthreads();
    if (t < 64) {
        float acc = b2[t];
        for (int k = 0; k < 128; ++k) acc += h1[k] * W2[k * 64 + t];
        h2v[t] = fmaxf(acc, 0.f);
    }
    __syncthreads();
    if (t < 32) {
        float acc = b3[t];
        for (int k = 0; k < 64; ++k) acc += h2v[k] * W3[k * 32 + t];
        h3v[t] = fmaxf(acc, 0.f);
    }
    __syncthreads();
    if (t == 0) {
        float acc = b4[0];
        for (int k = 0; k < 32; ++k) acc += h3v[k] * W4[k];
        out[b] = sigmoidf_(acc);
    }
}

extern "C" void kernel_launch(void* const* d_in, const int* in_sizes, int n_in,
                              void* d_out, int out_size, void* d_ws, size_t ws_size,
                              hipStream_t stream)
{
    const int*   node_slice = (const int*)d_in[0];
    const int*   type_slice = (const int*)d_in[1];
    const float* distance   = (const float*)d_in[2];
    const int*   rel_matrix = (const int*)d_in[3];
    const int*   input_len  = (const int*)d_in[4];
    // d_in[5] = isBatch (ignored)
    const float* emb_table  = (const float*)d_in[6];
    const float* type_table = (const float*)d_in[7];
    const float* rel_table  = (const float*)d_in[8];
    const float* W_in = (const float*)d_in[9];  const float* b_in = (const float*)d_in[10];
    const float* Wr   = (const float*)d_in[11]; const float* br   = (const float*)d_in[12];
    const float* Wz   = (const float*)d_in[13]; const float* bz   = (const float*)d_in[14];
    const float* Wt   = (const float*)d_in[15]; const float* bt   = (const float*)d_in[16];
    const float* W_co = (const float*)d_in[17]; const float* b_co = (const float*)d_in[18];
    const float* W1   = (const float*)d_in[19]; const float* b1   = (const float*)d_in[20];
    const float* W2   = (const float*)d_in[21]; const float* b2   = (const float*)d_in[22];
    const float* W3   = (const float*)d_in[23]; const float* b3   = (const float*)d_in[24];
    const float* W4   = (const float*)d_in[25]; const float* b4   = (const float*)d_in[26];

    u16* NTbf   = (u16*)d_ws;                                      // 6.29 MB
    u16* Hbf    = NTbf + (size_t)B_ * N_ * 192;                    // 2.10 MB
    u16* relWbG = Hbf + (size_t)B_ * N_ * 64;                      // 6.5 KB

    ggnn_pre<<<dim3(257), dim3(256), 0, stream>>>(
        node_slice, type_slice, emb_table, type_table,
        W_in, b_in, rel_table,
        Wr, br, Wz, bz, Wt, bt, NTbf, Hbf, relWbG);

    ggnn_main<<<dim3(B_), dim3(256), 0, stream>>>(
        rel_matrix, input_len, distance,
        Wr, Wz, Wt, W_in, W_co, b_co,
        W1, b1, W2, b2, W3, b3, W4, b4,
        NTbf, Hbf, relWbG, (float*)d_out);
}